// Round 7
// baseline (170.121 us; speedup 1.0000x reference)
//
#include <hip/hip_runtime.h>
#include <hip/hip_bf16.h>

#define D_DIM 768
#define K_CL  512
#define BM    32
#define BK    32
#define NSTEP 24          // 768 / 32

using f32x4 = __attribute__((ext_vector_type(4))) float;
using f32x2 = __attribute__((ext_vector_type(2))) float;
using s16x8 = __attribute__((ext_vector_type(8))) short;
using u16x8 = __attribute__((ext_vector_type(8))) unsigned short;
using u16x2 = __attribute__((ext_vector_type(2))) unsigned short;

static __device__ __forceinline__ unsigned short f2bf(float f) {
    __hip_bfloat16 h = __float2bfloat16(f);   // RTN
    unsigned short u;
    __builtin_memcpy(&u, &h, 2);
    return u;
}

// Prepass (unchanged from R5): C[512][768] fp32 -> bf16 ws in MFMA-fragment
// order: granule (16B = 8 bf16) g = t*2048 + (r>>6)*256 + ((r>>4)&3)*64
// + s*16 + (r&15) holds C[r][t*32 + s*8 .. +8).  Wave wn / lane loads frag
// (t,nf) at granule t*2048 + wn*256 + nf*64 + lane -> lane-linear coalesced.
__global__ void prep_centers_kernel(const float* __restrict__ C,
                                    unsigned short* __restrict__ Cbws,
                                    float* __restrict__ csq) {
    const int r = blockIdx.x;          // 0..511
    const int l = threadIdx.x;         // 0..63
    const float* src = C + (size_t)r * D_DIM;
    float sq = 0.f;
#pragma unroll
    for (int jj = 0; jj < 2; ++jj) {
        const int j = l + jj * 64;     // 0..127, only 0..95 valid
        if (j < 96) {
            const int t = j >> 2, s = j & 3;
            const int k0 = t * 32 + s * 8;
            f32x4 v0 = *reinterpret_cast<const f32x4*>(src + k0);
            f32x4 v1 = *reinterpret_cast<const f32x4*>(src + k0 + 4);
            u16x8 b;
            b[0] = f2bf(v0[0]); b[1] = f2bf(v0[1]); b[2] = f2bf(v0[2]); b[3] = f2bf(v0[3]);
            b[4] = f2bf(v1[0]); b[5] = f2bf(v1[1]); b[6] = f2bf(v1[2]); b[7] = f2bf(v1[3]);
            sq += v0[0]*v0[0] + v0[1]*v0[1] + v0[2]*v0[2] + v0[3]*v0[3]
                + v1[0]*v1[0] + v1[1]*v1[1] + v1[2]*v1[2] + v1[3]*v1[3];
            const int g = t * 2048 + (r >> 6) * 256 + ((r >> 4) & 3) * 64
                        + s * 16 + (r & 15);
            *reinterpret_cast<u16x8*>(Cbws + (size_t)g * 8) = b;
        }
    }
#pragma unroll
    for (int m = 1; m < 64; m <<= 1) sq += __shfl_xor(sq, m, 64);
    if (l == 0) csq[r] = sq;
}

// Main: 32 rows x 512 clusters per block, 8 waves, wave tile 32x64
// (acc[2][4] = 32 AGPR) -> ~85 regs/wave -> 3 blocks/CU (24 waves, 75% occ).
// A: reg->LDS dbuf (tiny, 4 KB). B: reg-direct from fragment-ordered ws.
__global__ __launch_bounds__(512, 6) void dec_main_kernel(
    const float* __restrict__ X,
    const unsigned short* __restrict__ Cbws,
    const float* __restrict__ csq,
    const float* __restrict__ alpha_ptr,
    float* __restrict__ out)
{
    __shared__ unsigned short Al[2][BM * BK];      // 2 * 2 KB
    __shared__ float part[8][BM];                  // 1 KB
    __shared__ float xsql[BM];
    __shared__ float invl[BM];

    const int tid  = threadIdx.x;      // 0..511
    const int lane = tid & 63;
    const int wn   = tid >> 6;         // 0..7
    const int m0   = blockIdx.x * BM;

    // A staging: 16 threads per row, f32x2 (8B) each
    const int arow = tid >> 4;                 // 0..31
    const int ac   = tid & 15;                 // col-pair index
    const float* aptr = X + (size_t)(m0 + arow) * D_DIM + ac * 2;
    // LDS write byte: row 64B; granule16 = ac>>2 XOR-swizzled, sub = ac&3
    const int awbyte = arow * 64
                     + (((ac >> 2) ^ ((arow >> 1) & 3)) << 4)
                     + (ac & 3) * 4;

    // fragment read base (same verified swizzle as R2-R5; 2-way max = free)
    const int fr = lane & 15;
    const int fg = lane >> 4;
    const int abase = fr * 64 + ((fg ^ ((fr >> 1) & 3)) << 4);  // + mf*1024

    // B fragment pointer (ushort units): frag(t,nf) at +(t*2048+nf*64)*8
    const unsigned short* bptr = Cbws + (size_t)(wn * 256 + lane) * 8;

    f32x4 acc[2][4] = {};
    s16x8 bA[4];
    float sqp = 0.f;

    // ---- prologue ----
    f32x2 areg = *reinterpret_cast<const f32x2*>(aptr);            // A tile 0
#pragma unroll
    for (int nf = 0; nf < 4; ++nf)
        bA[nf] = *reinterpret_cast<const s16x8*>(bptr + nf * 512); // B frags(0)
    {   // stage A(0)
        u16x2 ab;
        ab[0] = f2bf(areg[0]); ab[1] = f2bf(areg[1]);
        sqp += areg[0]*areg[0] + areg[1]*areg[1];
        *reinterpret_cast<u16x2*>((char*)&Al[0][0] + awbyte) = ab;
    }
    areg = *reinterpret_cast<const f32x2*>(aptr + BK);             // A tile 1
    asm volatile("s_waitcnt lgkmcnt(0)" ::: "memory");
    __builtin_amdgcn_sched_barrier(0);
    __builtin_amdgcn_s_barrier();

    for (int t = 0; t < NSTEP; ++t) {
        // compute(t): 2 A-frag ds_reads, 8 MFMA (B already in regs)
        {
            const char* ab = (const char*)&Al[t & 1][0] + abase;
            s16x8 afr0 = *reinterpret_cast<const s16x8*>(ab);
            s16x8 afr1 = *reinterpret_cast<const s16x8*>(ab + 1024);
            __builtin_amdgcn_s_setprio(1);
#pragma unroll
            for (int nf = 0; nf < 4; ++nf) {
                acc[0][nf] = __builtin_amdgcn_mfma_f32_16x16x32_bf16(
                    afr0, bA[nf], acc[0][nf], 0, 0, 0);
                acc[1][nf] = __builtin_amdgcn_mfma_f32_16x16x32_bf16(
                    afr1, bA[nf], acc[1][nf], 0, 0, 0);
            }
            __builtin_amdgcn_s_setprio(0);
        }
        if (t + 1 < NSTEP) {
            // reload B frags(t+1) (one full step of slack to land from L2)
            const unsigned short* bp = bptr + (size_t)(t + 1) * 16384;
#pragma unroll
            for (int nf = 0; nf < 4; ++nf)
                bA[nf] = *reinterpret_cast<const s16x8*>(bp + nf * 512);
            // stage A(t+1), prefetch A(t+2)
            u16x2 ab;
            ab[0] = f2bf(areg[0]); ab[1] = f2bf(areg[1]);
            sqp += areg[0]*areg[0] + areg[1]*areg[1];
            *reinterpret_cast<u16x2*>((char*)&Al[(t + 1) & 1][0] + awbyte) = ab;
            if (t + 2 < NSTEP)
                areg = *reinterpret_cast<const f32x2*>(aptr + (t + 2) * BK);
            asm volatile("s_waitcnt lgkmcnt(0)" ::: "memory");  // A writes visible
            __builtin_amdgcn_sched_barrier(0);
            __builtin_amdgcn_s_barrier();                       // B/a loads in flight
        }
    }

    // ---- ||x||^2 per row: reduce 16 staging threads ----
    sqp += __shfl_xor(sqp, 1, 64);
    sqp += __shfl_xor(sqp, 2, 64);
    sqp += __shfl_xor(sqp, 4, 64);
    sqp += __shfl_xor(sqp, 8, 64);
    if ((tid & 15) == 0) xsql[arow] = sqp;
    __syncthreads();

    const float alpha     = alpha_ptr[0];
    const float inv_alpha = 1.0f / alpha;
    const float power     = 0.5f * (alpha + 1.0f);
    const bool  p1        = (power == 1.0f);

    float csqr[4];
#pragma unroll
    for (int nf = 0; nf < 4; ++nf)
        csqr[nf] = csq[wn * 64 + nf * 16 + fr];

    if (p1) {
#pragma unroll
        for (int mf = 0; mf < 2; ++mf) {
#pragma unroll
            for (int j = 0; j < 4; ++j) {
                const int rloc = mf * 16 + fg * 4 + j;
                const float xs = xsql[rloc];
                float rp = 0.f;
#pragma unroll
                for (int nf = 0; nf < 4; ++nf) {
                    float d2 = xs + csqr[nf] - 2.0f * acc[mf][nf][j];
                    d2 = fmaxf(d2, 0.0f);
                    const float nm = 1.0f / (1.0f + d2 * inv_alpha);
                    acc[mf][nf][j] = nm;
                    rp += nm;
                }
#pragma unroll
                for (int m = 1; m < 16; m <<= 1) rp += __shfl_xor(rp, m, 64);
                if (fr == 0) part[wn][rloc] = rp;
            }
        }
    } else {
#pragma unroll
        for (int mf = 0; mf < 2; ++mf) {
#pragma unroll
            for (int j = 0; j < 4; ++j) {
                const int rloc = mf * 16 + fg * 4 + j;
                const float xs = xsql[rloc];
                float rp = 0.f;
#pragma unroll
                for (int nf = 0; nf < 4; ++nf) {
                    float d2 = xs + csqr[nf] - 2.0f * acc[mf][nf][j];
                    d2 = fmaxf(d2, 0.0f);
                    const float base = 1.0f + d2 * inv_alpha;
                    const float nm = exp2f(-power * log2f(base));
                    acc[mf][nf][j] = nm;
                    rp += nm;
                }
#pragma unroll
                for (int m = 1; m < 16; m <<= 1) rp += __shfl_xor(rp, m, 64);
                if (fr == 0) part[wn][rloc] = rp;
            }
        }
    }
    __syncthreads();
    if (tid < BM) {
        float s = 0.f;
#pragma unroll
        for (int w = 0; w < 8; ++w) s += part[w][tid];
        invl[tid] = 1.0f / s;
    }
    __syncthreads();

    // scaled store (16 consecutive lanes -> 64B contiguous segments)
#pragma unroll
    for (int mf = 0; mf < 2; ++mf) {
#pragma unroll
        for (int j = 0; j < 4; ++j) {
            const int rloc = mf * 16 + fg * 4 + j;
            const float iv = invl[rloc];
            float* orow = out + (size_t)(m0 + rloc) * K_CL + wn * 64 + fr;
#pragma unroll
            for (int nf = 0; nf < 4; ++nf)
                orow[nf * 16] = acc[mf][nf][j] * iv;
        }
    }
}

extern "C" void kernel_launch(void* const* d_in, const int* in_sizes, int n_in,
                              void* d_out, int out_size, void* d_ws, size_t ws_size,
                              hipStream_t stream) {
    const float* X     = (const float*)d_in[0];
    const float* C     = (const float*)d_in[1];
    const float* alpha = (const float*)d_in[2];
    float* out = (float*)d_out;
    const int N = in_sizes[0] / D_DIM;   // 65536

    unsigned short* Cbws = (unsigned short*)d_ws;
    float* csq = (float*)((char*)d_ws + (size_t)K_CL * D_DIM * sizeof(unsigned short));

    prep_centers_kernel<<<K_CL, 64, 0, stream>>>(C, Cbws, csq);
    dec_main_kernel<<<N / BM, 512, 0, stream>>>(X, Cbws, csq, alpha, out);
}

// Round 8
// 138.574 us; speedup vs baseline: 1.2277x; 1.2277x over previous
//
#include <hip/hip_runtime.h>
#include <hip/hip_bf16.h>

#define D_DIM 768
#define K_CL  512
#define BM    64
#define BK    96
#define NSTEP 8           // 768 / 96

using f32x4 = __attribute__((ext_vector_type(4))) float;
using s16x8 = __attribute__((ext_vector_type(8))) short;
using u16x8 = __attribute__((ext_vector_type(8))) unsigned short;
using u16x4 = __attribute__((ext_vector_type(4))) unsigned short;

static __device__ __forceinline__ unsigned short f2bf(float f) {
    __hip_bfloat16 h = __float2bfloat16(f);   // RTN
    unsigned short u;
    __builtin_memcpy(&u, &h, 2);
    return u;
}

// Prepass (unchanged, verified): C[512][768] fp32 -> bf16 ws in MFMA-fragment
// order: granule (16B = 8 bf16) g = t*2048 + (r>>6)*256 + ((r>>4)&3)*64
// + s*16 + (r&15) holds C[r][t*32 + s*8 .. +8).  t = 32-col tile index 0..23.
__global__ void prep_centers_kernel(const float* __restrict__ C,
                                    unsigned short* __restrict__ Cbws,
                                    float* __restrict__ csq) {
    const int r = blockIdx.x;          // 0..511
    const int l = threadIdx.x;         // 0..63
    const float* src = C + (size_t)r * D_DIM;
    float sq = 0.f;
#pragma unroll
    for (int jj = 0; jj < 2; ++jj) {
        const int j = l + jj * 64;     // 0..127, only 0..95 valid
        if (j < 96) {
            const int t = j >> 2, s = j & 3;
            const int k0 = t * 32 + s * 8;
            f32x4 v0 = *reinterpret_cast<const f32x4*>(src + k0);
            f32x4 v1 = *reinterpret_cast<const f32x4*>(src + k0 + 4);
            u16x8 b;
            b[0] = f2bf(v0[0]); b[1] = f2bf(v0[1]); b[2] = f2bf(v0[2]); b[3] = f2bf(v0[3]);
            b[4] = f2bf(v1[0]); b[5] = f2bf(v1[1]); b[6] = f2bf(v1[2]); b[7] = f2bf(v1[3]);
            sq += v0[0]*v0[0] + v0[1]*v0[1] + v0[2]*v0[2] + v0[3]*v0[3]
                + v1[0]*v1[0] + v1[1]*v1[1] + v1[2]*v1[2] + v1[3]*v1[3];
            const int g = t * 2048 + (r >> 6) * 256 + ((r >> 4) & 3) * 64
                        + s * 16 + (r & 15);
            *reinterpret_cast<u16x8*>(Cbws + (size_t)g * 8) = b;
        }
    }
#pragma unroll
    for (int m = 1; m < 64; m <<= 1) sq += __shfl_xor(sq, m, 64);
    if (l == 0) csq[r] = sq;
}

// Main: 64 rows x 512 clusters per block, 8 waves, wave tile 64x64.
// FAT K-steps: BK=96 (3 x 32-col sub-steps per barrier) -> 8 barriers total,
// 48 MFMA per wave-step, 384B-per-row X touches.  A: reg->LDS dbuf (24 KB,
// 2 blocks/CU).  B: reg-direct rotating bA[4], reloaded per sub-step
// (mid-step stalls are barrier-free, covered by 16 waves/CU).
__global__ __launch_bounds__(512, 4) void dec_main_kernel(
    const float* __restrict__ X,
    const unsigned short* __restrict__ Cbws,
    const float* __restrict__ csq,
    const float* __restrict__ alpha_ptr,
    float* __restrict__ out)
{
    __shared__ unsigned short Al[2][BM * BK];      // 2 * 12 KB (3 subtiles of 4 KB)
    __shared__ float part[8][BM];                  // 2 KB
    __shared__ float xsql[BM];
    __shared__ float invl[BM];

    const int tid  = threadIdx.x;      // 0..511
    const int lane = tid & 63;
    const int wn   = tid >> 6;         // 0..7
    const int m0   = blockIdx.x * BM;

    // A staging: 8 threads per row, f32x4 per subtile (3 subtiles/step)
    const int arow  = tid >> 3;        // 0..63
    const int acol8 = tid & 7;
    const float* aptr = X + (size_t)(m0 + arow) * D_DIM + acol8 * 4;
    const int awbyte = arow * 64
                     + ((((acol8 >> 1) ^ ((arow >> 1) & 3))) << 4)
                     + (acol8 & 1) * 8;            // within 4 KB subtile

    // fragment read base (verified swizzle); afr(mf,kk) at abase+mf*1024+kk*4096
    const int fr = lane & 15;
    const int fg = lane >> 4;
    const int abase = fr * 64 + ((fg ^ ((fr >> 1) & 3)) << 4);

    // B fragment pointer (ushort units): frag(t,nf) at +(t*16384 + nf*512)
    const unsigned short* bptr = Cbws + (size_t)(wn * 256 + lane) * 8;

    f32x4 acc[4][4] = {};
    s16x8 bA[4];
    float sqp = 0.f;

    // ---- staging helper (macro to keep regs tight) ----
#define STAGE_A(ar, dstbase, kk)                                               \
    {                                                                          \
        u16x4 ab_;                                                             \
        ab_[0] = f2bf((ar)[0]); ab_[1] = f2bf((ar)[1]);                        \
        ab_[2] = f2bf((ar)[2]); ab_[3] = f2bf((ar)[3]);                        \
        sqp += (ar)[0]*(ar)[0] + (ar)[1]*(ar)[1]                               \
             + (ar)[2]*(ar)[2] + (ar)[3]*(ar)[3];                              \
        *reinterpret_cast<u16x4*>((dstbase) + (kk) * 4096 + awbyte) = ab_;     \
    }

    // ---- prologue: A(0) regs, B(0,0) frags, stage A(0), A(1) regs ----
    f32x4 ar0 = *reinterpret_cast<const f32x4*>(aptr);
    f32x4 ar1 = *reinterpret_cast<const f32x4*>(aptr + 32);
    f32x4 ar2 = *reinterpret_cast<const f32x4*>(aptr + 64);
#pragma unroll
    for (int nf = 0; nf < 4; ++nf)
        bA[nf] = *reinterpret_cast<const s16x8*>(bptr + nf * 512);
    {
        char* dst = (char*)&Al[0][0];
        STAGE_A(ar0, dst, 0); STAGE_A(ar1, dst, 1); STAGE_A(ar2, dst, 2);
    }
    ar0 = *reinterpret_cast<const f32x4*>(aptr + BK);
    ar1 = *reinterpret_cast<const f32x4*>(aptr + BK + 32);
    ar2 = *reinterpret_cast<const f32x4*>(aptr + BK + 64);
    asm volatile("s_waitcnt lgkmcnt(0)" ::: "memory");
    __builtin_amdgcn_sched_barrier(0);
    __builtin_amdgcn_s_barrier();

    for (int T = 0; T < NSTEP; ++T) {
        const char* abuf = (const char*)&Al[T & 1][0];
#pragma unroll
        for (int kk = 0; kk < 3; ++kk) {
            // A frags for this sub-step
            s16x8 afr[4];
#pragma unroll
            for (int mf = 0; mf < 4; ++mf)
                afr[mf] = *reinterpret_cast<const s16x8*>(
                    abuf + kk * 4096 + abase + mf * 1024);
            __builtin_amdgcn_s_setprio(1);
#pragma unroll
            for (int nf = 0; nf < 4; ++nf) {
#pragma unroll
                for (int mf = 0; mf < 4; ++mf)
                    acc[mf][nf] = __builtin_amdgcn_mfma_f32_16x16x32_bf16(
                        afr[mf], bA[nf], acc[mf][nf], 0, 0, 0);
            }
            __builtin_amdgcn_s_setprio(0);
            // reload bA for next sub-step (or next step's kk=0)
            const int tn = T * 3 + kk + 1;      // next 32-col tile index
            if (tn < 24) {
                const unsigned short* bp = bptr + (size_t)tn * 16384;
#pragma unroll
                for (int nf = 0; nf < 4; ++nf)
                    bA[nf] = *reinterpret_cast<const s16x8*>(bp + nf * 512);
            }
        }
        if (T + 1 < NSTEP) {
            // stage A(T+1) into other buffer
            char* dst = (char*)&Al[(T + 1) & 1][0];
            STAGE_A(ar0, dst, 0); STAGE_A(ar1, dst, 1); STAGE_A(ar2, dst, 2);
            // prefetch A(T+2) regs
            if (T + 2 < NSTEP) {
                const float* ap = aptr + (T + 2) * BK;
                ar0 = *reinterpret_cast<const f32x4*>(ap);
                ar1 = *reinterpret_cast<const f32x4*>(ap + 32);
                ar2 = *reinterpret_cast<const f32x4*>(ap + 64);
            }
            asm volatile("s_waitcnt lgkmcnt(0)" ::: "memory");  // A writes visible
            __builtin_amdgcn_sched_barrier(0);
            __builtin_amdgcn_s_barrier();                       // loads stay in flight
        }
    }
#undef STAGE_A

    // ---- ||x||^2 per row: reduce 8 staging threads ----
    sqp += __shfl_xor(sqp, 1, 64);
    sqp += __shfl_xor(sqp, 2, 64);
    sqp += __shfl_xor(sqp, 4, 64);
    if ((tid & 7) == 0) xsql[arow] = sqp;
    __syncthreads();

    const float alpha     = alpha_ptr[0];
    const float inv_alpha = 1.0f / alpha;
    const float power     = 0.5f * (alpha + 1.0f);
    const bool  p1        = (power == 1.0f);

    float csqr[4];
#pragma unroll
    for (int nf = 0; nf < 4; ++nf)
        csqr[nf] = csq[wn * 64 + nf * 16 + fr];

    if (p1) {
#pragma unroll
        for (int mf = 0; mf < 4; ++mf) {
#pragma unroll
            for (int j = 0; j < 4; ++j) {
                const int rloc = mf * 16 + fg * 4 + j;
                const float xs = xsql[rloc];
                float rp = 0.f;
#pragma unroll
                for (int nf = 0; nf < 4; ++nf) {
                    float d2 = xs + csqr[nf] - 2.0f * acc[mf][nf][j];
                    d2 = fmaxf(d2, 0.0f);
                    const float nm = 1.0f / (1.0f + d2 * inv_alpha);
                    acc[mf][nf][j] = nm;
                    rp += nm;
                }
#pragma unroll
                for (int m = 1; m < 16; m <<= 1) rp += __shfl_xor(rp, m, 64);
                if (fr == 0) part[wn][rloc] = rp;
            }
        }
    } else {
#pragma unroll
        for (int mf = 0; mf < 4; ++mf) {
#pragma unroll
            for (int j = 0; j < 4; ++j) {
                const int rloc = mf * 16 + fg * 4 + j;
                const float xs = xsql[rloc];
                float rp = 0.f;
#pragma unroll
                for (int nf = 0; nf < 4; ++nf) {
                    float d2 = xs + csqr[nf] - 2.0f * acc[mf][nf][j];
                    d2 = fmaxf(d2, 0.0f);
                    const float base = 1.0f + d2 * inv_alpha;
                    const float nm = exp2f(-power * log2f(base));
                    acc[mf][nf][j] = nm;
                    rp += nm;
                }
#pragma unroll
                for (int m = 1; m < 16; m <<= 1) rp += __shfl_xor(rp, m, 64);
                if (fr == 0) part[wn][rloc] = rp;
            }
        }
    }
    __syncthreads();
    if (tid < BM) {
        float s = 0.f;
#pragma unroll
        for (int w = 0; w < 8; ++w) s += part[w][tid];
        invl[tid] = 1.0f / s;
    }
    __syncthreads();

    // scaled store (16 consecutive lanes -> 64B contiguous segments)
#pragma unroll
    for (int mf = 0; mf < 4; ++mf) {
#pragma unroll
        for (int j = 0; j < 4; ++j) {
            const int rloc = mf * 16 + fg * 4 + j;
            const float iv = invl[rloc];
            float* orow = out + (size_t)(m0 + rloc) * K_CL + wn * 64 + fr;
#pragma unroll
            for (int nf = 0; nf < 4; ++nf)
                orow[nf * 16] = acc[mf][nf][j] * iv;
        }
    }
}

extern "C" void kernel_launch(void* const* d_in, const int* in_sizes, int n_in,
                              void* d_out, int out_size, void* d_ws, size_t ws_size,
                              hipStream_t stream) {
    const float* X     = (const float*)d_in[0];
    const float* C     = (const float*)d_in[1];
    const float* alpha = (const float*)d_in[2];
    float* out = (float*)d_out;
    const int N = in_sizes[0] / D_DIM;   // 65536

    unsigned short* Cbws = (unsigned short*)d_ws;
    float* csq = (float*)((char*)d_ws + (size_t)K_CL * D_DIM * sizeof(unsigned short));

    prep_centers_kernel<<<K_CL, 64, 0, stream>>>(C, Cbws, csq);
    dec_main_kernel<<<N / BM, 512, 0, stream>>>(X, Cbws, csq, alpha, out);
}